// Round 10
// baseline (41.064 us; speedup 1.0000x reference)
//
#include <hip/hip_runtime.h>

#define N_    2
#define C_    128
#define H_    128
#define W_    128
#define COUT_ 128
#define K_    9
#define HO_   128
#define WO_   128
#define HW_   (H_*W_)

typedef __attribute__((ext_vector_type(8))) short  short8v;
typedef __attribute__((ext_vector_type(4))) float  float4v;
typedef __attribute__((ext_vector_type(2))) float  float2v;
typedef __attribute__((ext_vector_type(4))) unsigned int uint4v;

__device__ __forceinline__ unsigned short f2bf(float f) {
    union { float f; unsigned int u; } v; v.f = f;
    return (unsigned short)((v.u + 0x7FFFu + ((v.u >> 16) & 1u)) >> 16);  // RNE
}
__device__ __forceinline__ float bflo(unsigned int u) {
    union { unsigned int u; float f; } v; v.u = u << 16; return v.f;
}
__device__ __forceinline__ float bfhi(unsigned int u) {
    union { unsigned int u; float f; } v; v.u = u & 0xFFFF0000u; return v.f;
}
__device__ __forceinline__ unsigned int cvt_pk_bf16(float lo, float hi) {
    unsigned int r;
    asm("v_cvt_pk_bf16_f32 %0, %1, %2" : "=v"(r) : "v"(lo), "v"(hi));  // RNE pack
    return r;
}

// ---- one-time prep: weight pack (A-fragment order) + CHW->HWC bf16 --------
__global__ __launch_bounds__(256)
void prep(const float* __restrict__ x, const float* __restrict__ w,
          unsigned short* __restrict__ xT, unsigned short* __restrict__ wb) {
    if (blockIdx.x >= 256) {                       // ---- pack_w part
        const int t = (blockIdx.x - 256) * 256 + threadIdx.x;
        if (t >= 9 * 8 * 4 * 64) return;
        const int l  = t & 63;
        const int ks = (t >> 6) & 3;
        const int mt = (t >> 8) & 7;
        const int kk = t >> 11;
        const int row = mt * 16 + (l & 15);
        const int c0  = ks * 32 + (l >> 4) * 8;
        unsigned short pk[8];
        #pragma unroll
        for (int j = 0; j < 8; ++j)
            pk[j] = f2bf(w[row * (C_ * K_) + (c0 + j) * K_ + kk]);
        *((short8v*)wb + t) = *(short8v*)pk;
        return;
    }
    // ---- xpose part: one n (bid>>7), 128 pixels
    __shared__ unsigned short tile[128][136];
    const int t  = threadIdx.x;
    const int n  = blockIdx.x >> 7;
    const int p0 = (blockIdx.x & 127) * 128;
    #pragma unroll 4
    for (int i = 0; i < 32; ++i) {
        const int q = i * 2 + (t >> 7);
        const int p = t & 127;
        const float v0 = x[((size_t)(n * C_ + 2 * q    )) * HW_ + p0 + p];
        const float v1 = x[((size_t)(n * C_ + 2 * q + 1)) * HW_ + p0 + p];
        const unsigned int u = (unsigned int)f2bf(v0) | ((unsigned int)f2bf(v1) << 16);
        *(unsigned int*)&tile[p][2 * q] = u;
    }
    __syncthreads();
    const int p    = t >> 1;
    const int half = t & 1;
    unsigned short* dst = xT + ((size_t)(n * HW_ + p0 + p) << 7) + half * 64;
    #pragma unroll
    for (int j = 0; j < 8; ++j)
        *(short8v*)(dst + j * 8) = *(short8v*)&tile[p][half * 64 + j * 8];
}

// ---- fused deformable-im2col + MFMA GEMM -----------------------------------
// 512 blocks x 512 threads (64-px tiles). Wave = 32 cout x 32 px. Gather uses
// 16-lanes-per-256B-row mapping (dense TA segments: 4 rows/instr, each fully
// contiguous). Single non-draining barrier per tap; 1-tap gather prefetch.
__global__ __launch_bounds__(512, 4)
void dcn_mfma(const unsigned short* __restrict__ xT,
              const float* __restrict__ offset,
              const float* __restrict__ mask,
              const unsigned short* __restrict__ wbuf,
              const float* __restrict__ bias,
              float* __restrict__ out)
{
    __shared__ unsigned short colsT[2][64 * 128]; // 32 KB double-buffered
    __shared__ int4   samp_a[K_ * 64];            // 9.2 KB
    __shared__ float4 samp_w[K_ * 64];            // 9.2 KB

    const int tid = threadIdx.x;
    const int lid = (blockIdx.x & 7) * 64 + (blockIdx.x >> 3);  // XCD swizzle
    const int n   = lid >> 8;
    const int ho  = (lid >> 1) & 127;
    const int wo0 = (lid & 1) * 64;

    // ---- metadata for all 9 taps x 64 pixels ------------------------------
    for (int e = tid; e < K_ * 64; e += 512) {
        const int kk  = e >> 6;
        const int wol = e & 63;
        const int wo  = wo0 + wol;
        const int iy = kk / 3, ix = kk % 3;
        const int ob = ((n * 2 * K_ + 2 * kk) * HO_ + ho) * WO_ + wo;
        const float offy = offset[ob];
        const float offx = offset[ob + HO_ * WO_];
        const float m    = mask[((n * K_ + kk) * HO_ + ho) * WO_ + wo];
        const float ys = (float)(ho - 1 + iy) + offy;
        const float xs = (float)(wo - 1 + ix) + offx;
        const float y0f = floorf(ys), x0f = floorf(xs);
        const float ly = ys - y0f, lx = xs - x0f;
        const int y0 = (int)y0f, x0 = (int)x0f;
        const int y1 = y0 + 1,  x1 = x0 + 1;
        const float vy0 = (y0 >= 0 && y0 < H_) ? 1.f : 0.f;
        const float vy1 = (y1 >= 0 && y1 < H_) ? 1.f : 0.f;
        const float vx0 = (x0 >= 0 && x0 < W_) ? 1.f : 0.f;
        const float vx1 = (x1 >= 0 && x1 < W_) ? 1.f : 0.f;
        const int y0c = min(max(y0, 0), H_-1), y1c = min(max(y1, 0), H_-1);
        const int x0c = min(max(x0, 0), W_-1), x1c = min(max(x1, 0), W_-1);
        samp_a[e] = make_int4(y0c*W_+x0c, y0c*W_+x1c, y1c*W_+x0c, y1c*W_+x1c);
        samp_w[e] = make_float4((1.f-ly)*(1.f-lx)*m*vy0*vx0,
                                (1.f-ly)*lx      *m*vy0*vx1,
                                ly      *(1.f-lx)*m*vy1*vx0,
                                ly      *lx      *m*vy1*vx1);
    }
    __syncthreads();

    const int lane   = tid & 63;
    const int wv     = tid >> 6;        // wave 0..7
    const int s16    = lane & 15;       // 16B chunk within a 256B channel row
    const int p4     = lane >> 4;       // 4 staging pixels per gather instr
    const int mslice = wv >> 1;         // cout slice 0..3
    const int nslice = wv & 1;          // px half 0..1
    const int mt0    = mslice * 2;
    const int nt0    = nslice * 2;
    float4v acc[2][2] = {};             // 32 cout x 32 px per wave

    const char* xb = (const char*)xT + (size_t)n * HW_ * 256;
    const short8v* wb = (const short8v*)wbuf;

    // ---- prologue: tap-0 gathers (16 lanes span one 256B row densely) -----
    uint4v ga[2][4];
    float4 w4g[2];
    #pragma unroll
    for (int g = 0; g < 2; ++g) {
        const int ps = wv * 8 + g * 4 + p4;         // staging pixel 0..63
        const int4 rows = samp_a[ps];
        w4g[g] = samp_w[ps];
        ga[g][0] = *(const uint4v*)(xb + (size_t)rows.x * 256 + s16*16);
        ga[g][1] = *(const uint4v*)(xb + (size_t)rows.y * 256 + s16*16);
        ga[g][2] = *(const uint4v*)(xb + (size_t)rows.z * 256 + s16*16);
        ga[g][3] = *(const uint4v*)(xb + (size_t)rows.w * 256 + s16*16);
    }

    #pragma unroll
    for (int kk = 0; kk < K_; ++kk) {
        const int cur = kk & 1;

        // ---- issue this tap's A-fragments ---------------------------------
        short8v af[2][4];
        #pragma unroll
        for (int ks = 0; ks < 4; ++ks) {
            af[0][ks] = wb[((kk * 8 + mt0    ) * 4 + ks) * 64 + lane];
            af[1][ks] = wb[((kk * 8 + mt0 + 1) * 4 + ks) * 64 + lane];
        }

        // ---- packed bilinear combine + cvt_pk pack ------------------------
        uint4v res[2];
        #pragma unroll
        for (int g = 0; g < 2; ++g) {
            const float2v wx = {w4g[g].x, w4g[g].x};
            const float2v wy = {w4g[g].y, w4g[g].y};
            const float2v wz = {w4g[g].z, w4g[g].z};
            const float2v ww = {w4g[g].w, w4g[g].w};
            #pragma unroll
            for (int j = 0; j < 4; ++j) {
                const unsigned int u00 = ga[g][0][j], u01 = ga[g][1][j];
                const unsigned int u10 = ga[g][2][j], u11 = ga[g][3][j];
                const float2v f00 = {bflo(u00), bfhi(u00)};
                const float2v f01 = {bflo(u01), bfhi(u01)};
                const float2v f10 = {bflo(u10), bfhi(u10)};
                const float2v f11 = {bflo(u11), bfhi(u11)};
                const float2v v = wx*f00 + wy*f01 + wz*f10 + ww*f11;
                res[g][j] = cvt_pk_bf16(v[0], v[1]);
            }
        }

        // ---- prefetch tap kk+1 gathers ------------------------------------
        if (kk < K_ - 1) {
            #pragma unroll
            for (int g = 0; g < 2; ++g) {
                const int ps = wv * 8 + g * 4 + p4;
                const int4 rows = samp_a[(kk + 1) * 64 + ps];
                w4g[g] = samp_w[(kk + 1) * 64 + ps];
                ga[g][0] = *(const uint4v*)(xb + (size_t)rows.x * 256 + s16*16);
                ga[g][1] = *(const uint4v*)(xb + (size_t)rows.y * 256 + s16*16);
                ga[g][2] = *(const uint4v*)(xb + (size_t)rows.z * 256 + s16*16);
                ga[g][3] = *(const uint4v*)(xb + (size_t)rows.w * 256 + s16*16);
            }
        }

        // ---- publish into LDS buffer `cur` --------------------------------
        {
            char* cb = (char*)colsT[cur];
            #pragma unroll
            for (int g = 0; g < 2; ++g) {
                const int ps = wv * 8 + g * 4 + p4;
                const int byte = (ps * 256 + s16 * 16) ^ ((ps & 7) << 4);
                *(uint4v*)(cb + byte) = res[g];
            }
        }

        // ---- non-draining barrier: LDS drained, VMEM stays in flight ------
        asm volatile("s_waitcnt lgkmcnt(0)" ::: "memory");
        __builtin_amdgcn_s_barrier();

        // ---- MFMA: 4 k-steps x 2 n-tiles x 2 m-tiles ----------------------
        __builtin_amdgcn_s_setprio(1);
        #pragma unroll
        for (int ks = 0; ks < 4; ++ks) {
            short8v b[2];
            #pragma unroll
            for (int ntl = 0; ntl < 2; ++ntl) {
                const int row = (nt0 + ntl) * 16 + (lane & 15);
                const int byte = (row * 256 + ks * 64 + (lane >> 4) * 16)
                               ^ ((row & 7) << 4);
                b[ntl] = *(const short8v*)((const char*)colsT[cur] + byte);
            }
            #pragma unroll
            for (int ntl = 0; ntl < 2; ++ntl) {
                acc[0][ntl] = __builtin_amdgcn_mfma_f32_16x16x32_bf16(af[0][ks], b[ntl], acc[0][ntl], 0, 0, 0);
                acc[1][ntl] = __builtin_amdgcn_mfma_f32_16x16x32_bf16(af[1][ks], b[ntl], acc[1][ntl], 0, 0, 0);
            }
        }
        __builtin_amdgcn_s_setprio(0);
    }

    // ---- epilogue: D layout col=lane&15 (wo), row=(lane>>4)*4+reg (cout) --
    const int colw  = lane & 15;
    const int rquad = (lane >> 4) * 4;
    #pragma unroll
    for (int mi = 0; mi < 2; ++mi) {
        #pragma unroll
        for (int ntl = 0; ntl < 2; ++ntl) {
            const int woe = wo0 + (nt0 + ntl) * 16 + colw;
            #pragma unroll
            for (int r = 0; r < 4; ++r) {
                const int co = (mt0 + mi) * 16 + rquad + r;
                out[((size_t)(n * COUT_ + co) * HO_ + ho) * WO_ + woe] = acc[mi][ntl][r] + bias[co];
            }
        }
    }
}

extern "C" void kernel_launch(void* const* d_in, const int* in_sizes, int n_in,
                              void* d_out, int out_size, void* d_ws, size_t ws_size,
                              hipStream_t stream) {
    const float* x      = (const float*)d_in[0];
    const float* offset = (const float*)d_in[1];
    const float* mask   = (const float*)d_in[2];
    const float* weight = (const float*)d_in[3];
    const float* bias   = (const float*)d_in[4];
    float* out = (float*)d_out;

    unsigned short* xT   = (unsigned short*)d_ws;                    // 8,388,608 B
    unsigned short* wbuf = (unsigned short*)((char*)d_ws + 8388608); // +294,912 B

    prep<<<328, 256, 0, stream>>>(x, weight, xT, wbuf);
    dcn_mfma<<<N_ * HO_ * 2, 512, 0, stream>>>(xT, offset, mask, wbuf, bias, out);
}

// Round 11
// 38.445 us; speedup vs baseline: 1.0681x; 1.0681x over previous
//
#include <hip/hip_runtime.h>

#define N_    2
#define C_    128
#define H_    128
#define W_    128
#define COUT_ 128
#define K_    9
#define HO_   128
#define WO_   128
#define HW_   (H_*W_)

typedef __attribute__((ext_vector_type(8))) short  short8v;
typedef __attribute__((ext_vector_type(4))) float  float4v;
typedef __attribute__((ext_vector_type(2))) float  float2v;
typedef __attribute__((ext_vector_type(4))) unsigned int uint4v;

__device__ __forceinline__ unsigned short f2bf(float f) {
    union { float f; unsigned int u; } v; v.f = f;
    return (unsigned short)((v.u + 0x7FFFu + ((v.u >> 16) & 1u)) >> 16);  // RNE
}
__device__ __forceinline__ float bflo(unsigned int u) {
    union { unsigned int u; float f; } v; v.u = u << 16; return v.f;
}
__device__ __forceinline__ float bfhi(unsigned int u) {
    union { unsigned int u; float f; } v; v.u = u & 0xFFFF0000u; return v.f;
}
__device__ __forceinline__ unsigned int cvt_pk_bf16(float lo, float hi) {
    unsigned int r;
    asm("v_cvt_pk_bf16_f32 %0, %1, %2" : "=v"(r) : "v"(lo), "v"(hi));  // RNE pack
    return r;
}

// ---- one-time prep: weight pack (A-fragment order) + CHW->HWC bf16 --------
__global__ __launch_bounds__(256)
void prep(const float* __restrict__ x, const float* __restrict__ w,
          unsigned short* __restrict__ xT, unsigned short* __restrict__ wb) {
    if (blockIdx.x >= 256) {                       // ---- pack_w part
        const int t = (blockIdx.x - 256) * 256 + threadIdx.x;
        if (t >= 9 * 8 * 4 * 64) return;
        const int l  = t & 63;
        const int ks = (t >> 6) & 3;
        const int mt = (t >> 8) & 7;
        const int kk = t >> 11;
        const int row = mt * 16 + (l & 15);
        const int c0  = ks * 32 + (l >> 4) * 8;
        unsigned short pk[8];
        #pragma unroll
        for (int j = 0; j < 8; ++j)
            pk[j] = f2bf(w[row * (C_ * K_) + (c0 + j) * K_ + kk]);
        *((short8v*)wb + t) = *(short8v*)pk;
        return;
    }
    // ---- xpose part: one n (bid>>7), 128 pixels
    __shared__ unsigned short tile[128][136];
    const int t  = threadIdx.x;
    const int n  = blockIdx.x >> 7;
    const int p0 = (blockIdx.x & 127) * 128;
    #pragma unroll 4
    for (int i = 0; i < 32; ++i) {
        const int q = i * 2 + (t >> 7);
        const int p = t & 127;
        const float v0 = x[((size_t)(n * C_ + 2 * q    )) * HW_ + p0 + p];
        const float v1 = x[((size_t)(n * C_ + 2 * q + 1)) * HW_ + p0 + p];
        const unsigned int u = (unsigned int)f2bf(v0) | ((unsigned int)f2bf(v1) << 16);
        *(unsigned int*)&tile[p][2 * q] = u;
    }
    __syncthreads();
    const int p    = t >> 1;
    const int half = t & 1;
    unsigned short* dst = xT + ((size_t)(n * HW_ + p0 + p) << 7) + half * 64;
    #pragma unroll
    for (int j = 0; j < 8; ++j)
        *(short8v*)(dst + j * 8) = *(short8v*)&tile[p][half * 64 + j * 8];
}

// ---- fused deformable-im2col + MFMA GEMM, PRODUCER/CONSUMER waves ---------
// 512 blocks x 512 threads (64-px tile). Waves 0-3 = producers (gather +
// bilinear combine + publish), waves 4-7 = consumers (A-load + LDS-read +
// MFMA, 32 cout x 64 px each). Interval k: producers build tap k+1 into
// buf[(k+1)&1] while consumers compute tap k from buf[k&1]; one barrier per
// interval. Gather/A latency covered by a full interval + opposite-role waves.
__global__ __launch_bounds__(512, 4)
void dcn_mfma(const unsigned short* __restrict__ xT,
              const float* __restrict__ offset,
              const float* __restrict__ mask,
              const unsigned short* __restrict__ wbuf,
              const float* __restrict__ bias,
              float* __restrict__ out)
{
    __shared__ unsigned short colsT[2][64 * 128]; // 32 KB double-buffered
    __shared__ int4   samp_a[K_ * 64];            // 9.2 KB
    __shared__ float4 samp_w[K_ * 64];            // 9.2 KB

    const int tid = threadIdx.x;
    const int lid = (blockIdx.x & 7) * 64 + (blockIdx.x >> 3);  // XCD swizzle
    const int n   = lid >> 8;
    const int ho  = (lid >> 1) & 127;
    const int wo0 = (lid & 1) * 64;

    // ---- metadata for all 9 taps x 64 pixels (all threads) ----------------
    for (int e = tid; e < K_ * 64; e += 512) {
        const int kk  = e >> 6;
        const int wol = e & 63;
        const int wo  = wo0 + wol;
        const int iy = kk / 3, ix = kk % 3;
        const int ob = ((n * 2 * K_ + 2 * kk) * HO_ + ho) * WO_ + wo;
        const float offy = offset[ob];
        const float offx = offset[ob + HO_ * WO_];
        const float m    = mask[((n * K_ + kk) * HO_ + ho) * WO_ + wo];
        const float ys = (float)(ho - 1 + iy) + offy;
        const float xs = (float)(wo - 1 + ix) + offx;
        const float y0f = floorf(ys), x0f = floorf(xs);
        const float ly = ys - y0f, lx = xs - x0f;
        const int y0 = (int)y0f, x0 = (int)x0f;
        const int y1 = y0 + 1,  x1 = x0 + 1;
        const float vy0 = (y0 >= 0 && y0 < H_) ? 1.f : 0.f;
        const float vy1 = (y1 >= 0 && y1 < H_) ? 1.f : 0.f;
        const float vx0 = (x0 >= 0 && x0 < W_) ? 1.f : 0.f;
        const float vx1 = (x1 >= 0 && x1 < W_) ? 1.f : 0.f;
        const int y0c = min(max(y0, 0), H_-1), y1c = min(max(y1, 0), H_-1);
        const int x0c = min(max(x0, 0), W_-1), x1c = min(max(x1, 0), W_-1);
        samp_a[e] = make_int4(y0c*W_+x0c, y0c*W_+x1c, y1c*W_+x0c, y1c*W_+x1c);
        samp_w[e] = make_float4((1.f-ly)*(1.f-lx)*m*vy0*vx0,
                                (1.f-ly)*lx      *m*vy0*vx1,
                                ly      *(1.f-lx)*m*vy1*vx0,
                                ly      *lx      *m*vy1*vx1);
    }
    __syncthreads();

    const int lane = tid & 63;
    const int wv   = tid >> 6;
    const int wvu  = __builtin_amdgcn_readfirstlane(wv);  // scalar branch
    const char* xb = (const char*)xT + (size_t)n * HW_ * 256;

    if (wvu < 4) {
        // ===================== PRODUCER waves ==============================
        const int s16 = lane & 15;          // 16B chunk within 256B px row
        const int ph  = lane >> 4;          // px sub-index

        auto build = [&](int kk, int buf) {
            uint4v ga[4][4];                // [px-group][corner]
            float4 w4g[4];
            #pragma unroll
            for (int pg = 0; pg < 4; ++pg) {
                const int px = wvu * 16 + pg * 4 + ph;
                const int4 rows = samp_a[kk * 64 + px];
                w4g[pg] = samp_w[kk * 64 + px];
                ga[pg][0] = *(const uint4v*)(xb + (size_t)rows.x * 256 + s16 * 16);
                ga[pg][1] = *(const uint4v*)(xb + (size_t)rows.y * 256 + s16 * 16);
                ga[pg][2] = *(const uint4v*)(xb + (size_t)rows.z * 256 + s16 * 16);
                ga[pg][3] = *(const uint4v*)(xb + (size_t)rows.w * 256 + s16 * 16);
            }
            char* cb = (char*)colsT[buf];
            #pragma unroll
            for (int pg = 0; pg < 4; ++pg) {
                const float2v wx = {w4g[pg].x, w4g[pg].x};
                const float2v wy = {w4g[pg].y, w4g[pg].y};
                const float2v wz = {w4g[pg].z, w4g[pg].z};
                const float2v ww = {w4g[pg].w, w4g[pg].w};
                uint4v res;
                #pragma unroll
                for (int j = 0; j < 4; ++j) {
                    const unsigned int u00 = ga[pg][0][j], u01 = ga[pg][1][j];
                    const unsigned int u10 = ga[pg][2][j], u11 = ga[pg][3][j];
                    const float2v f00 = {bflo(u00), bfhi(u00)};
                    const float2v f01 = {bflo(u01), bfhi(u01)};
                    const float2v f10 = {bflo(u10), bfhi(u10)};
                    const float2v f11 = {bflo(u11), bfhi(u11)};
                    const float2v v = wx*f00 + wy*f01 + wz*f10 + ww*f11;
                    res[j] = cvt_pk_bf16(v[0], v[1]);
                }
                const int px = wvu * 16 + pg * 4 + ph;
                const int byte = (px * 256 + s16 * 16) ^ ((px & 7) << 4);
                *(uint4v*)(cb + byte) = res;
            }
        };

        build(0, 0);                        // prologue: tap 0 -> buf 0
        asm volatile("s_waitcnt lgkmcnt(0)" ::: "memory");
        __builtin_amdgcn_s_barrier();
        __builtin_amdgcn_sched_barrier(0);
        for (int kk = 0; kk < K_; ++kk) {
            if (kk < K_ - 1) build(kk + 1, (kk + 1) & 1);
            asm volatile("s_waitcnt lgkmcnt(0)" ::: "memory");
            __builtin_amdgcn_s_barrier();
            __builtin_amdgcn_sched_barrier(0);
        }
    } else {
        // ===================== CONSUMER waves ==============================
        const int wvc = wvu - 4;            // 0..3
        const int mt0 = wvc * 2;            // 2 cout-tiles of 16 (32 cout)
        const short8v* wb = (const short8v*)wbuf;
        float4v acc[2][4] = {};             // 32 cout x 64 px

        asm volatile("s_waitcnt lgkmcnt(0)" ::: "memory");
        __builtin_amdgcn_s_barrier();       // matches producer prologue
        __builtin_amdgcn_sched_barrier(0);

        for (int kk = 0; kk < K_; ++kk) {
            short8v af0[4], af1[4];
            #pragma unroll
            for (int ks = 0; ks < 4; ++ks) {
                af0[ks] = wb[((kk * 8 + mt0    ) * 4 + ks) * 64 + lane];
                af1[ks] = wb[((kk * 8 + mt0 + 1) * 4 + ks) * 64 + lane];
            }
            const char* cb = (const char*)colsT[kk & 1];
            __builtin_amdgcn_s_setprio(1);
            #pragma unroll
            for (int ks = 0; ks < 4; ++ks) {
                short8v b[4];
                #pragma unroll
                for (int nt = 0; nt < 4; ++nt) {
                    const int row = nt * 16 + (lane & 15);
                    const int byte = (row * 256 + ks * 64 + (lane >> 4) * 16)
                                   ^ ((row & 7) << 4);
                    b[nt] = *(const short8v*)(cb + byte);
                }
                #pragma unroll
                for (int nt = 0; nt < 4; ++nt) {
                    acc[0][nt] = __builtin_amdgcn_mfma_f32_16x16x32_bf16(af0[ks], b[nt], acc[0][nt], 0, 0, 0);
                    acc[1][nt] = __builtin_amdgcn_mfma_f32_16x16x32_bf16(af1[ks], b[nt], acc[1][nt], 0, 0, 0);
                }
            }
            __builtin_amdgcn_s_setprio(0);
            asm volatile("s_waitcnt lgkmcnt(0)" ::: "memory");
            __builtin_amdgcn_s_barrier();
            __builtin_amdgcn_sched_barrier(0);
        }

        // ---- epilogue: D layout col=lane&15 (wo), row=(lane>>4)*4+reg -----
        const int colw  = lane & 15;
        const int rquad = (lane >> 4) * 4;
        #pragma unroll
        for (int mi = 0; mi < 2; ++mi) {
            #pragma unroll
            for (int nt = 0; nt < 4; ++nt) {
                const int woe = wo0 + nt * 16 + colw;
                #pragma unroll
                for (int r = 0; r < 4; ++r) {
                    const int co = (mt0 + mi) * 16 + rquad + r;
                    out[((size_t)(n * COUT_ + co) * HO_ + ho) * WO_ + woe] = acc[mi][nt][r] + bias[co];
                }
            }
        }
    }
}

extern "C" void kernel_launch(void* const* d_in, const int* in_sizes, int n_in,
                              void* d_out, int out_size, void* d_ws, size_t ws_size,
                              hipStream_t stream) {
    const float* x      = (const float*)d_in[0];
    const float* offset = (const float*)d_in[1];
    const float* mask   = (const float*)d_in[2];
    const float* weight = (const float*)d_in[3];
    const float* bias   = (const float*)d_in[4];
    float* out = (float*)d_out;

    unsigned short* xT   = (unsigned short*)d_ws;                    // 8,388,608 B
    unsigned short* wbuf = (unsigned short*)((char*)d_ws + 8388608); // +294,912 B

    prep<<<328, 256, 0, stream>>>(x, weight, xT, wbuf);
    dcn_mfma<<<N_ * HO_ * 2, 512, 0, stream>>>(xT, offset, mask, wbuf, bias, out);
}

// Round 12
// 37.828 us; speedup vs baseline: 1.0856x; 1.0163x over previous
//
#include <hip/hip_runtime.h>

#define N_    2
#define C_    128
#define H_    128
#define W_    128
#define COUT_ 128
#define K_    9
#define HO_   128
#define WO_   128
#define HW_   (H_*W_)

typedef __attribute__((ext_vector_type(8))) short  short8v;
typedef __attribute__((ext_vector_type(4))) float  float4v;
typedef __attribute__((ext_vector_type(2))) float  float2v;
typedef __attribute__((ext_vector_type(4))) unsigned int uint4v;

__device__ __forceinline__ unsigned short f2bf(float f) {
    union { float f; unsigned int u; } v; v.f = f;
    return (unsigned short)((v.u + 0x7FFFu + ((v.u >> 16) & 1u)) >> 16);  // RNE
}
__device__ __forceinline__ float bflo(unsigned int u) {
    union { unsigned int u; float f; } v; v.u = u << 16; return v.f;
}
__device__ __forceinline__ float bfhi(unsigned int u) {
    union { unsigned int u; float f; } v; v.u = u & 0xFFFF0000u; return v.f;
}
__device__ __forceinline__ unsigned int cvt_pk_bf16(float lo, float hi) {
    unsigned int r;
    asm("v_cvt_pk_bf16_f32 %0, %1, %2" : "=v"(r) : "v"(lo), "v"(hi));  // RNE pack
    return r;
}

// ---- one-time prep: weight pack (A-fragment order) + CHW->HWC bf16 --------
__global__ __launch_bounds__(256)
void prep(const float* __restrict__ x, const float* __restrict__ w,
          unsigned short* __restrict__ xT, unsigned short* __restrict__ wb) {
    if (blockIdx.x >= 256) {                       // ---- pack_w part
        const int t = (blockIdx.x - 256) * 256 + threadIdx.x;
        if (t >= 9 * 8 * 4 * 64) return;
        const int l  = t & 63;
        const int ks = (t >> 6) & 3;
        const int mt = (t >> 8) & 7;
        const int kk = t >> 11;
        const int row = mt * 16 + (l & 15);
        const int c0  = ks * 32 + (l >> 4) * 8;
        unsigned short pk[8];
        #pragma unroll
        for (int j = 0; j < 8; ++j)
            pk[j] = f2bf(w[row * (C_ * K_) + (c0 + j) * K_ + kk]);
        *((short8v*)wb + t) = *(short8v*)pk;
        return;
    }
    // ---- xpose part: one n (bid>>7), 128 pixels
    __shared__ unsigned short tile[128][136];
    const int t  = threadIdx.x;
    const int n  = blockIdx.x >> 7;
    const int p0 = (blockIdx.x & 127) * 128;
    #pragma unroll 4
    for (int i = 0; i < 32; ++i) {
        const int q = i * 2 + (t >> 7);
        const int p = t & 127;
        const float v0 = x[((size_t)(n * C_ + 2 * q    )) * HW_ + p0 + p];
        const float v1 = x[((size_t)(n * C_ + 2 * q + 1)) * HW_ + p0 + p];
        const unsigned int u = (unsigned int)f2bf(v0) | ((unsigned int)f2bf(v1) << 16);
        *(unsigned int*)&tile[p][2 * q] = u;
    }
    __syncthreads();
    const int p    = t >> 1;
    const int half = t & 1;
    unsigned short* dst = xT + ((size_t)(n * HW_ + p0 + p) << 7) + half * 64;
    #pragma unroll
    for (int j = 0; j < 8; ++j)
        *(short8v*)(dst + j * 8) = *(short8v*)&tile[p][half * 64 + j * 8];
}

// ---- fused deformable-im2col + MFMA GEMM, PRODUCER/CONSUMER waves ---------
// 512 blocks x 512 threads (64-px tile). Waves 0-3 = producers, 4-7 =
// consumers. PRODUCER PIPELINE (new vs R11): per pixel-group rotation —
// combine+publish tap k+1 group pg (regs loaded during interval k-1), then
// immediately issue tap k+2 group pg into the same registers. Every gather
// gets ~a full interval of latency cover instead of stalling at point of use.
__global__ __launch_bounds__(512, 4)
void dcn_mfma(const unsigned short* __restrict__ xT,
              const float* __restrict__ offset,
              const float* __restrict__ mask,
              const unsigned short* __restrict__ wbuf,
              const float* __restrict__ bias,
              float* __restrict__ out)
{
    __shared__ unsigned short colsT[2][64 * 128]; // 32 KB double-buffered
    __shared__ int4   samp_a[K_ * 64];            // 9.2 KB
    __shared__ float4 samp_w[K_ * 64];            // 9.2 KB

    const int tid = threadIdx.x;
    const int lid = (blockIdx.x & 7) * 64 + (blockIdx.x >> 3);  // XCD swizzle
    const int n   = lid >> 8;
    const int ho  = (lid >> 1) & 127;
    const int wo0 = (lid & 1) * 64;

    // ---- metadata for all 9 taps x 64 pixels (all threads) ----------------
    for (int e = tid; e < K_ * 64; e += 512) {
        const int kk  = e >> 6;
        const int wol = e & 63;
        const int wo  = wo0 + wol;
        const int iy = kk / 3, ix = kk % 3;
        const int ob = ((n * 2 * K_ + 2 * kk) * HO_ + ho) * WO_ + wo;
        const float offy = offset[ob];
        const float offx = offset[ob + HO_ * WO_];
        const float m    = mask[((n * K_ + kk) * HO_ + ho) * WO_ + wo];
        const float ys = (float)(ho - 1 + iy) + offy;
        const float xs = (float)(wo - 1 + ix) + offx;
        const float y0f = floorf(ys), x0f = floorf(xs);
        const float ly = ys - y0f, lx = xs - x0f;
        const int y0 = (int)y0f, x0 = (int)x0f;
        const int y1 = y0 + 1,  x1 = x0 + 1;
        const float vy0 = (y0 >= 0 && y0 < H_) ? 1.f : 0.f;
        const float vy1 = (y1 >= 0 && y1 < H_) ? 1.f : 0.f;
        const float vx0 = (x0 >= 0 && x0 < W_) ? 1.f : 0.f;
        const float vx1 = (x1 >= 0 && x1 < W_) ? 1.f : 0.f;
        const int y0c = min(max(y0, 0), H_-1), y1c = min(max(y1, 0), H_-1);
        const int x0c = min(max(x0, 0), W_-1), x1c = min(max(x1, 0), W_-1);
        samp_a[e] = make_int4(y0c*W_+x0c, y0c*W_+x1c, y1c*W_+x0c, y1c*W_+x1c);
        samp_w[e] = make_float4((1.f-ly)*(1.f-lx)*m*vy0*vx0,
                                (1.f-ly)*lx      *m*vy0*vx1,
                                ly      *(1.f-lx)*m*vy1*vx0,
                                ly      *lx      *m*vy1*vx1);
    }
    __syncthreads();

    const int lane = tid & 63;
    const int wv   = tid >> 6;
    const int wvu  = __builtin_amdgcn_readfirstlane(wv);  // scalar branch
    const char* xb = (const char*)xT + (size_t)n * HW_ * 256;

    if (wvu < 4) {
        // ===================== PRODUCER waves ==============================
        const int s16 = lane & 15;          // 16B chunk within 256B px row
        const int ph  = lane >> 4;          // px sub-index

        uint4v ga[4][4];                    // [px-group][corner] rotating set
        float4 w4g[4];

        // issue group pg's 4 corner loads for tap kk
        auto issue = [&](int kk, int pg_) {
            const int px = wvu * 16 + pg_ * 4 + ph;
            const int4 rows = samp_a[kk * 64 + px];
            w4g[pg_] = samp_w[kk * 64 + px];
            ga[pg_][0] = *(const uint4v*)(xb + (size_t)rows.x * 256 + s16 * 16);
            ga[pg_][1] = *(const uint4v*)(xb + (size_t)rows.y * 256 + s16 * 16);
            ga[pg_][2] = *(const uint4v*)(xb + (size_t)rows.z * 256 + s16 * 16);
            ga[pg_][3] = *(const uint4v*)(xb + (size_t)rows.w * 256 + s16 * 16);
        };
        // combine group pg (regs) and publish into tap kk's buffer
        auto publish = [&](int kk, int pg_) {
            const float2v wx = {w4g[pg_].x, w4g[pg_].x};
            const float2v wy = {w4g[pg_].y, w4g[pg_].y};
            const float2v wz = {w4g[pg_].z, w4g[pg_].z};
            const float2v ww = {w4g[pg_].w, w4g[pg_].w};
            uint4v res;
            #pragma unroll
            for (int j = 0; j < 4; ++j) {
                const unsigned int u00 = ga[pg_][0][j], u01 = ga[pg_][1][j];
                const unsigned int u10 = ga[pg_][2][j], u11 = ga[pg_][3][j];
                const float2v f00 = {bflo(u00), bfhi(u00)};
                const float2v f01 = {bflo(u01), bfhi(u01)};
                const float2v f10 = {bflo(u10), bfhi(u10)};
                const float2v f11 = {bflo(u11), bfhi(u11)};
                const float2v v = wx*f00 + wy*f01 + wz*f10 + ww*f11;
                res[j] = cvt_pk_bf16(v[0], v[1]);
            }
            const int px = wvu * 16 + pg_ * 4 + ph;
            const int byte = (px * 256 + s16 * 16) ^ ((px & 7) << 4);
            *(uint4v*)((char*)colsT[kk & 1] + byte) = res;
        };

        // prologue: tap0 load+publish, then issue tap1
        #pragma unroll
        for (int pg = 0; pg < 4; ++pg) issue(0, pg);
        #pragma unroll
        for (int pg = 0; pg < 4; ++pg) { publish(0, pg); issue(1, pg); }
        asm volatile("s_waitcnt lgkmcnt(0)" ::: "memory");
        __builtin_amdgcn_s_barrier();
        __builtin_amdgcn_sched_barrier(0);

        #pragma unroll
        for (int kk = 0; kk < K_; ++kk) {
            if (kk < K_ - 1) {
                #pragma unroll
                for (int pg = 0; pg < 4; ++pg) {
                    publish(kk + 1, pg);            // regs from interval kk-1
                    if (kk + 2 < K_) issue(kk + 2, pg);  // cover: ~full interval
                }
            }
            asm volatile("s_waitcnt lgkmcnt(0)" ::: "memory");
            __builtin_amdgcn_s_barrier();
            __builtin_amdgcn_sched_barrier(0);
        }
    } else {
        // ===================== CONSUMER waves (identical to R11) ===========
        const int wvc = wvu - 4;            // 0..3
        const int mt0 = wvc * 2;            // 2 cout-tiles of 16 (32 cout)
        const short8v* wb = (const short8v*)wbuf;
        float4v acc[2][4] = {};             // 32 cout x 64 px

        asm volatile("s_waitcnt lgkmcnt(0)" ::: "memory");
        __builtin_amdgcn_s_barrier();       // matches producer prologue
        __builtin_amdgcn_sched_barrier(0);

        for (int kk = 0; kk < K_; ++kk) {
            short8v af0[4], af1[4];
            #pragma unroll
            for (int ks = 0; ks < 4; ++ks) {
                af0[ks] = wb[((kk * 8 + mt0    ) * 4 + ks) * 64 + lane];
                af1[ks] = wb[((kk * 8 + mt0 + 1) * 4 + ks) * 64 + lane];
            }
            const char* cb = (const char*)colsT[kk & 1];
            __builtin_amdgcn_s_setprio(1);
            #pragma unroll
            for (int ks = 0; ks < 4; ++ks) {
                short8v b[4];
                #pragma unroll
                for (int nt = 0; nt < 4; ++nt) {
                    const int row = nt * 16 + (lane & 15);
                    const int byte = (row * 256 + ks * 64 + (lane >> 4) * 16)
                                   ^ ((row & 7) << 4);
                    b[nt] = *(const short8v*)(cb + byte);
                }
                #pragma unroll
                for (int nt = 0; nt < 4; ++nt) {
                    acc[0][nt] = __builtin_amdgcn_mfma_f32_16x16x32_bf16(af0[ks], b[nt], acc[0][nt], 0, 0, 0);
                    acc[1][nt] = __builtin_amdgcn_mfma_f32_16x16x32_bf16(af1[ks], b[nt], acc[1][nt], 0, 0, 0);
                }
            }
            __builtin_amdgcn_s_setprio(0);
            asm volatile("s_waitcnt lgkmcnt(0)" ::: "memory");
            __builtin_amdgcn_s_barrier();
            __builtin_amdgcn_sched_barrier(0);
        }

        // ---- epilogue: D layout col=lane&15 (wo), row=(lane>>4)*4+reg -----
        const int colw  = lane & 15;
        const int rquad = (lane >> 4) * 4;
        #pragma unroll
        for (int mi = 0; mi < 2; ++mi) {
            #pragma unroll
            for (int nt = 0; nt < 4; ++nt) {
                const int woe = wo0 + nt * 16 + colw;
                #pragma unroll
                for (int r = 0; r < 4; ++r) {
                    const int co = (mt0 + mi) * 16 + rquad + r;
                    out[((size_t)(n * COUT_ + co) * HO_ + ho) * WO_ + woe] = acc[mi][nt][r] + bias[co];
                }
            }
        }
    }
}

extern "C" void kernel_launch(void* const* d_in, const int* in_sizes, int n_in,
                              void* d_out, int out_size, void* d_ws, size_t ws_size,
                              hipStream_t stream) {
    const float* x      = (const float*)d_in[0];
    const float* offset = (const float*)d_in[1];
    const float* mask   = (const float*)d_in[2];
    const float* weight = (const float*)d_in[3];
    const float* bias   = (const float*)d_in[4];
    float* out = (float*)d_out;

    unsigned short* xT   = (unsigned short*)d_ws;                    // 8,388,608 B
    unsigned short* wbuf = (unsigned short*)((char*)d_ws + 8388608); // +294,912 B

    prep<<<328, 256, 0, stream>>>(x, weight, xT, wbuf);
    dcn_mfma<<<N_ * HO_ * 2, 512, 0, stream>>>(xT, offset, mask, wbuf, bias, out);
}